// Round 6
// baseline (340.224 us; speedup 1.0000x reference)
//
#include <hip/hip_runtime.h>

typedef unsigned short u16;
typedef unsigned int u32;
typedef __attribute__((ext_vector_type(8))) short short8v;   // 8 bf16 MFMA frag
typedef __attribute__((ext_vector_type(4))) float f32x4;
typedef __attribute__((ext_vector_type(2))) float f32x2;
typedef __attribute__((ext_vector_type(4))) unsigned int uint4v;
typedef __attribute__((ext_vector_type(2))) unsigned int uint2v;
typedef __attribute__((ext_vector_type(8))) unsigned short us8;
typedef __attribute__((ext_vector_type(4))) unsigned short us4;

#define B_   4
#define S_   19950
#define C_   256
#define NH   8
#define DH   32
#define BS_  (B_*S_)          // 79800

#define BM 128
#define BN 128
#define KC 32                 // K-chunk per pipeline step (8 steps over K=256)

__device__ __forceinline__ float bf2f(u16 u){ u32 x=((u32)u)<<16; float f; __builtin_memcpy(&f,&x,4); return f; }
__device__ __forceinline__ u16 f2bf(float f){ u32 x; __builtin_memcpy(&x,&f,4); x += 0x7fffu + ((x>>16)&1u); return (u16)(x>>16); }
__device__ __forceinline__ u32 cvtpk(float a, float b){ u32 r; asm("v_cvt_pk_bf16_f32 %0, %1, %2" : "=v"(r) : "v"(a), "v"(b)); return r; }
__device__ __forceinline__ f32x2 pkfma(f32x2 a, f32x2 b, f32x2 d){
  asm("v_pk_fma_f32 %0, %1, %2, %0" : "+v"(d) : "v"(a), "v"(b)); return d;
}
__device__ __forceinline__ f32x2 unpk(u32 p){
  uint2v u; u.x = p<<16; u.y = p & 0xffff0000u; return __builtin_bit_cast(f32x2, u);
}

// ================= MFMA GEMM core: C[M,N] = A[M,256] * W[N,256]^T =================
// MODE 0: A=value f32 -> v bf16 permuted (b,h,s,dh);  MODE 1: A=query f32 -> soff + softmaxed sattn
// MODE 2: A=tmp bf16  -> out f32.
// Pipeline: T3-minimal 2-phase. Both A and B staged f32 (bf16 for MODE2-A) via
// global_load_lds, double-buffered; XOR swizzle realized by inverse-swizzling the
// per-lane SOURCE address (LDS dest linear) and XOR on the read side.
// Per k-step: STAGE(next); s_waitcnt vmcnt(N); s_barrier; compute; s_barrier.
template<int MODE>
__device__ __forceinline__ void gemm_core(
    const void* __restrict__ Aany, const float* __restrict__ Wmain,
    const float* __restrict__ Wattn, const float* __restrict__ bmain,
    const float* __restrict__ battn, void* __restrict__ out0, u16* __restrict__ out1)
{
  constexpr int NX = (MODE==1) ? 3 : 2;
  __shared__ u32 AsU[8192];   // 32 KB: A dbuf. MODE0/1: f32[2][128][32]; MODE2: bf16[2][64 lines][64]
  __shared__ u32 BsU[8192];   // 32 KB: B dbuf f32[2][128][32]
  float* Asf = (float*)AsU;
  u16*  Asb  = (u16*)AsU;
  float* Bsf = (float*)BsU;

  const int tid = threadIdx.x;
  const int g = blockIdx.x;
  const int x = (g>>3) % NX;
  const int y = ((g>>3)/NX)*8 + (g&7);   // XCD-paired: col-blocks of one A-panel 8 apart -> same XCD
  const int m0 = y * BM;
  const int n0 = x * BN;
  const int lane = tid & 63;
  const int wid  = tid >> 6;
  const int wm = wid >> 1, wn = wid & 1;
  const int ln15 = lane & 15, ln4 = lane >> 4;

  f32x4 acc[4][4];
  #pragma unroll
  for (int i=0;i<4;++i){
    #pragma unroll
    for (int j=0;j<4;++j) acc[i][j] = (f32x4){0.f,0.f,0.f,0.f};
  }

  // ---- staging helpers (DMA; dest linear wave-uniform + lane*16B; source pre-swizzled) ----
  auto stageA = [&](int bi, int k0){
    if constexpr (MODE==2) {
      const u16* Ab = (const u16*)Aany;
      #pragma unroll
      for (int i=0;i<2;++i){
        const int ll = wid*16 + i*8 + (lane>>3);        // line 0..63 (2 rows per 128B line)
        const int p  = lane & 7;
        const int orig = p ^ (ll & 7);
        const int row = ll*2 + (orig>>2);
        const int c = orig & 3;
        const int rg = min(m0 + row, BS_-1);
        __builtin_amdgcn_global_load_lds(Ab + (size_t)rg*C_ + k0 + c*8,
            (u16*)&Asb[bi*4096 + (wid*16 + i*8)*64], 16, 0, 0);
      }
    } else {
      const float* Ab = (const float*)Aany;
      #pragma unroll
      for (int i=0;i<4;++i){
        const int rl = wid*32 + i*8 + (lane>>3);        // row 0..127
        const int rg = min(m0 + rl, BS_-1);
        const int c = lane & 7, cs = c ^ (rl & 7);
        __builtin_amdgcn_global_load_lds(Ab + (size_t)rg*C_ + k0 + cs*4,
            (float*)&Asf[bi*4096 + (wid*32 + i*8)*32], 16, 0, 0);
      }
    }
  };
  auto stageB = [&](int bi, int k0){
    #pragma unroll
    for (int i=0;i<4;++i){
      const int rl = wid*32 + i*8 + (lane>>3);
      const int c = lane & 7, cs = c ^ (rl & 7);
      const float* src;
      if constexpr (MODE==1) {
        const int n = n0 + rl;
        src = (n < 192) ? (Wmain + (size_t)n*C_) : (Wattn + (size_t)(min(n,287)-192)*C_);
      } else {
        src = Wmain + (size_t)(n0 + rl)*C_;
      }
      __builtin_amdgcn_global_load_lds(src + k0 + cs*4,
          (float*)&Bsf[bi*4096 + (wid*32 + i*8)*32], 16, 0, 0);
    }
  };

  // ---- prologue ----
  stageA(0, 0);
  stageB(0, 0);

  for (int t=0; t<8; ++t) {
    const int bi = t & 1;
    if (t < 7) {
      stageA(bi^1, (t+1)*KC);
      stageB(bi^1, (t+1)*KC);
      if constexpr (MODE==2) asm volatile("s_waitcnt vmcnt(6)" ::: "memory");
      else                   asm volatile("s_waitcnt vmcnt(8)" ::: "memory");
    } else {
      asm volatile("s_waitcnt vmcnt(0)" ::: "memory");
    }
    __builtin_amdgcn_s_barrier();
    __builtin_amdgcn_sched_barrier(0);

    // ---- compute one K-chunk of 32 ----
    short8v af[4], bfr[4];
    #pragma unroll
    for (int mi=0;mi<4;++mi){
      const int row = wm*64 + mi*16 + ln15;
      if constexpr (MODE==2) {
        const int ll = row>>1;
        const int p = ((row&1)*4 + ln4) ^ (ll&7);
        af[mi] = *(const short8v*)&Asb[bi*4096 + ll*64 + p*8];
      } else {
        const int c1 = (2*ln4) ^ (row&7), c2 = c1 ^ 1;
        const f32x4 lo = *(const f32x4*)&Asf[bi*4096 + row*32 + c1*4];
        const f32x4 hi = *(const f32x4*)&Asf[bi*4096 + row*32 + c2*4];
        uint4v uu;
        uu.x = cvtpk(lo.x, lo.y); uu.y = cvtpk(lo.z, lo.w);
        uu.z = cvtpk(hi.x, hi.y); uu.w = cvtpk(hi.z, hi.w);
        af[mi] = __builtin_bit_cast(short8v, uu);
      }
    }
    #pragma unroll
    for (int ni=0;ni<4;++ni){
      const int row = wn*64 + ni*16 + ln15;
      const int c1 = (2*ln4) ^ (row&7), c2 = c1 ^ 1;
      const f32x4 lo = *(const f32x4*)&Bsf[bi*4096 + row*32 + c1*4];
      const f32x4 hi = *(const f32x4*)&Bsf[bi*4096 + row*32 + c2*4];
      uint4v uu;
      uu.x = cvtpk(lo.x, lo.y); uu.y = cvtpk(lo.z, lo.w);
      uu.z = cvtpk(hi.x, hi.y); uu.w = cvtpk(hi.z, hi.w);
      bfr[ni] = __builtin_bit_cast(short8v, uu);
    }
    #pragma unroll
    for (int mi=0;mi<4;++mi){
      #pragma unroll
      for (int ni=0;ni<4;++ni)
        acc[mi][ni] = __builtin_amdgcn_mfma_f32_16x16x32_bf16(af[mi], bfr[ni], acc[mi][ni], 0, 0, 0);
    }

    __builtin_amdgcn_sched_barrier(0);
    __builtin_amdgcn_s_barrier();
  }

  // ---- epilogue (validated round 2/4) ----
  #pragma unroll
  for (int mi=0;mi<4;++mi){
    #pragma unroll
    for (int ni=0;ni<4;++ni){
      const int n = n0 + wn*64 + ni*16 + ln15;
      if (MODE==1 && n >= 288) continue;
      float bias;
      if constexpr (MODE==1) bias = (n < 192) ? bmain[n] : battn[n-192];
      else                   bias = bmain[n];
      if (MODE==1 && n >= 192) {
        #pragma unroll
        for (int j=0;j<4;++j){
          const int m = m0 + wm*64 + mi*16 + ln4*4 + j;
          const float vv = acc[mi][ni][j] + bias;
          float mx = vv;
          mx = fmaxf(mx, __shfl_xor(mx, 1));
          mx = fmaxf(mx, __shfl_xor(mx, 2));
          const float e = __expf(vv - mx);
          float ssum = e;
          ssum += __shfl_xor(ssum, 1);
          ssum += __shfl_xor(ssum, 2);
          if (m < BS_) out1[(size_t)m*96 + (n-192)] = f2bf(e/ssum);
        }
      } else if (MODE==1) {
        u16* soff = (u16*)out0;
        #pragma unroll
        for (int j=0;j<4;++j){
          const int m = m0 + wm*64 + mi*16 + ln4*4 + j;
          if (m < BS_) soff[(size_t)m*192 + n] = f2bf(acc[mi][ni][j] + bias);
        }
      } else if (MODE==0) {
        u16* vout = (u16*)out0;
        const int h = n >> 5, dh = n & 31;
        #pragma unroll
        for (int j=0;j<4;++j){
          const int m = m0 + wm*64 + mi*16 + ln4*4 + j;
          if (m < BS_) {
            const int bq = m / S_, s = m - bq*S_;
            vout[((size_t)(bq*NH+h)*S_ + s)*DH + dh] = f2bf(acc[mi][ni][j] + bias);
          }
        }
      } else {
        float* outp = (float*)out0;
        #pragma unroll
        for (int j=0;j<4;++j){
          const int m = m0 + wm*64 + mi*16 + ln4*4 + j;
          if (m < BS_) outp[(size_t)m*C_ + n] = acc[mi][ni][j] + bias;
        }
      }
    }
  }
}

// Plain (non-template) kernels -> host stubs always emitted.
__global__ __launch_bounds__(256) void k_gemm0(const void* __restrict__ A,
    const float* __restrict__ W, const float* __restrict__ b, void* __restrict__ o)
{ gemm_core<0>(A, W, nullptr, b, nullptr, o, nullptr); }

__global__ __launch_bounds__(256) void k_gemm1(const void* __restrict__ A,
    const float* __restrict__ Wm, const float* __restrict__ Wa,
    const float* __restrict__ bm, const float* __restrict__ ba,
    void* __restrict__ o0, u16* __restrict__ o1)
{ gemm_core<1>(A, Wm, Wa, bm, ba, o0, o1); }

__global__ __launch_bounds__(256) void k_gemm2(const void* __restrict__ A,
    const float* __restrict__ W, const float* __restrict__ b, void* __restrict__ o)
{ gemm_core<2>(A, W, nullptr, b, nullptr, o, nullptr); }

// ================= Sampler v4: 8 ch/thread, 32-bit offsets, NT streaming =================
#define NCH 312   // ceil(19950/64) chunks of 64 queries

__global__ __launch_bounds__(256) void k_sample4(const u16* __restrict__ v,
    const u16* __restrict__ soff, const u16* __restrict__ sattn,
    const float* __restrict__ refp, u16* __restrict__ tmp)
{
  const int g = blockIdx.x;
  const int xcd = g & 7, inner = g >> 3;
  const int unit = inner / NCH;               // 0..3
  const int cidx = inner - unit*NCH;
  const int bh = xcd*4 + unit;                // 4 (b,h)-slices per XCD for L2 locality
  const int b = bh >> 3, h = bh & 7;
  const int dh0 = (threadIdx.x & 3) * 8;
  const int q = cidx*64 + (threadIdx.x >> 2);
  if (q >= S_) return;
  const size_t r = (size_t)b*S_ + q;
  const f32x2 rp = __builtin_nontemporal_load((const f32x2*)(refp + r*2));
  const float refx = rp.x, refy = rp.y;
  const char* vb = (const char*)(v + (size_t)bh * S_ * DH);

  const u16* sop = soff + r*192 + h*24;
  const u16* sap = sattn + r*96 + h*12;
  us8 so0 = __builtin_nontemporal_load((const us8*)(sop));
  us8 so1 = __builtin_nontemporal_load((const us8*)(sop + 8));
  us8 so2 = __builtin_nontemporal_load((const us8*)(sop + 16));
  us4 sa0 = __builtin_nontemporal_load((const us4*)(sap));
  us4 sa1 = __builtin_nontemporal_load((const us4*)(sap + 4));
  us4 sa2 = __builtin_nontemporal_load((const us4*)(sap + 8));
  u16 soarr[24]; u16 saarr[12];
  #pragma unroll
  for (int i=0;i<8;++i){ soarr[i]=so0[i]; soarr[8+i]=so1[i]; soarr[16+i]=so2[i]; }
  #pragma unroll
  for (int i=0;i<4;++i){ saarr[i]=sa0[i]; saarr[4+i]=sa1[i]; saarr[8+i]=sa2[i]; }

  f32x2 acc0 = (f32x2){0.f,0.f}, acc1 = acc0, acc2 = acc0, acc3 = acc0;
  const int WLs[3]={152,76,38}, HLs[3]={100,50,25}, STs[3]={0,15200,19000};
  const u32 ch2 = (u32)(dh0*2);
  #pragma unroll
  for (int l=0;l<3;++l) {
    const int Wl=WLs[l], Hl=HLs[l];
    const float rxl = refx*(float)Wl - 0.5f;   // ix = ref*W + off - 0.5 (normalizer folded)
    const float ryl = refy*(float)Hl - 0.5f;
    const char* vbl = vb + (size_t)STs[l]*DH*2;
    #pragma unroll
    for (int p=0;p<4;++p) {
      const int idx = l*4 + p;
      const float ix = rxl + bf2f(soarr[2*idx+0]);
      const float iy = ryl + bf2f(soarr[2*idx+1]);
      const float aw = bf2f(saarr[idx]);
      const float x0f = floorf(ix), y0f = floorf(iy);
      const float wx1 = ix-x0f, wy1 = iy-y0f;
      const int x0 = (int)x0f, y0 = (int)y0f;
      const int x1 = x0+1, y1 = y0+1;
      // zeroed separable weights (validity folded), aw folded into y factors
      const float wx0z = ((u32)x0 < (u32)Wl) ? (1.f-wx1) : 0.f;
      const float wx1z = ((u32)x1 < (u32)Wl) ? wx1 : 0.f;
      const float wy0z = ((u32)y0 < (u32)Hl) ? aw*(1.f-wy1) : 0.f;
      const float wy1z = ((u32)y1 < (u32)Hl) ? aw*wy1 : 0.f;
      const int xi0 = min(max(x0,0),Wl-1), xi1 = min(max(x1,0),Wl-1);
      const int yi0 = min(max(y0,0),Hl-1), yi1 = min(max(y1,0),Hl-1);
      const u32 rb0 = (u32)(yi0*Wl)*64u + ch2;
      const u32 rb1 = (u32)(yi1*Wl)*64u + ch2;
      const uint4v t00 = *(const uint4v*)(vbl + rb0 + (u32)xi0*64u);
      const uint4v t01 = *(const uint4v*)(vbl + rb0 + (u32)xi1*64u);
      const uint4v t10 = *(const uint4v*)(vbl + rb1 + (u32)xi0*64u);
      const uint4v t11 = *(const uint4v*)(vbl + rb1 + (u32)xi1*64u);
      const float w00 = wx0z*wy0z, w01 = wx1z*wy0z;
      const float w10 = wx0z*wy1z, w11 = wx1z*wy1z;
      f32x2 W00 = (f32x2){w00,w00}, W01 = (f32x2){w01,w01};
      f32x2 W10 = (f32x2){w10,w10}, W11 = (f32x2){w11,w11};
      acc0 = pkfma(unpk(t00.x), W00, acc0);
      acc1 = pkfma(unpk(t00.y), W00, acc1);
      acc2 = pkfma(unpk(t00.z), W00, acc2);
      acc3 = pkfma(unpk(t00.w), W00, acc3);
      acc0 = pkfma(unpk(t01.x), W01, acc0);
      acc1 = pkfma(unpk(t01.y), W01, acc1);
      acc2 = pkfma(unpk(t01.z), W01, acc2);
      acc3 = pkfma(unpk(t01.w), W01, acc3);
      acc0 = pkfma(unpk(t10.x), W10, acc0);
      acc1 = pkfma(unpk(t10.y), W10, acc1);
      acc2 = pkfma(unpk(t10.z), W10, acc2);
      acc3 = pkfma(unpk(t10.w), W10, acc3);
      acc0 = pkfma(unpk(t11.x), W11, acc0);
      acc1 = pkfma(unpk(t11.y), W11, acc1);
      acc2 = pkfma(unpk(t11.z), W11, acc2);
      acc3 = pkfma(unpk(t11.w), W11, acc3);
    }
  }
  uint4v o;
  o.x = cvtpk(acc0.x, acc0.y); o.y = cvtpk(acc1.x, acc1.y);
  o.z = cvtpk(acc2.x, acc2.y); o.w = cvtpk(acc3.x, acc3.y);
  __builtin_nontemporal_store(o, (uint4v*)(tmp + r*C_ + (size_t)h*DH + dh0));
}

extern "C" void kernel_launch(void* const* d_in, const int* in_sizes, int n_in,
                              void* d_out, int out_size, void* d_ws, size_t ws_size,
                              hipStream_t stream) {
  (void)in_sizes; (void)n_in; (void)out_size; (void)ws_size;
  const float* query = (const float*)d_in[0];
  const float* value = (const float*)d_in[1];
  const float* refp  = (const float*)d_in[4];
  const float* W_off = (const float*)d_in[5];
  const float* b_off = (const float*)d_in[6];
  const float* W_attn= (const float*)d_in[7];
  const float* b_attn= (const float*)d_in[8];
  const float* W_val = (const float*)d_in[9];
  const float* b_val = (const float*)d_in[10];
  const float* W_out = (const float*)d_in[11];
  const float* b_out = (const float*)d_in[12];
  float* out = (float*)d_out;

  char* ws = (char*)d_ws;
  constexpr size_t V_BYTES    = (size_t)BS_*C_*2;     // 40.9 MB: v bf16 (b,h,s,dh)
  constexpr size_t SOFF_BYTES = (size_t)BS_*192*2;    // 30.6 MB
  constexpr size_t SATTN_BYTES= (size_t)BS_*96*2;     // 15.3 MB
  u16* v     = (u16*)(ws);
  u16* soff  = (u16*)(ws + V_BYTES);
  u16* sattn = (u16*)(ws + V_BYTES + SOFF_BYTES);
  u16* tmp   = (u16*)(ws + V_BYTES + SOFF_BYTES + SATTN_BYTES);

  dim3 blk(256);
  hipLaunchKernelGGL(k_gemm0, dim3(2*624), blk, 0, stream,
                     (const void*)value, W_val, b_val, (void*)v);
  hipLaunchKernelGGL(k_gemm1, dim3(3*624), blk, 0, stream,
                     (const void*)query, W_off, W_attn, b_off, b_attn,
                     (void*)soff, sattn);
  hipLaunchKernelGGL(k_sample4, dim3(8*4*NCH), blk, 0, stream, v, soff, sattn, refp, tmp);
  hipLaunchKernelGGL(k_gemm2, dim3(2*624), blk, 0, stream,
                     (const void*)tmp, W_out, b_out, (void*)out);
}